// Round 2
// baseline (1347.659 us; speedup 1.0000x reference)
//
#include <hip/hip_runtime.h>
#include <math.h>

#define NN 100000
#define NE 1600000

__device__ __forceinline__ float lrelu(float t) { return t >= 0.0f ? t : 0.2f * t; }

// float atomic max via int/uint trick (works for all sign combos, init -inf)
__device__ __forceinline__ void atomicMaxF(float* addr, float v) {
    if (v >= 0.0f) atomicMax((int*)addr, __float_as_int(v));
    else           atomicMin((unsigned int*)addr, __float_as_uint(v));
}

__global__ void k_init_m(float* __restrict__ m) {
    int i = blockIdx.x * blockDim.x + threadIdx.x;
    if (i < NN * 4) m[i] = __int_as_float(0xff800000);  // -inf
}

// h = x @ W^T (fp64 acc), att logits a_src/a_dst via per-head shuffle reduce.
// block = 256 = 4 waves; wave handles one node row (lane = channel).
__global__ __launch_bounds__(256) void k_proj(
    const float* __restrict__ x, const float* __restrict__ pw,
    const float* __restrict__ atts, const float* __restrict__ attd,
    float* __restrict__ h, float* __restrict__ asrc, float* __restrict__ adst) {
    __shared__ float w[64][65];   // pad 65: banks (c+k)%32, conflict-free
    __shared__ float xs[4][64];
    int tid = threadIdx.x;
    for (int i = tid; i < 4096; i += 256) w[i >> 6][i & 63] = pw[i];
    int lane = tid & 63, wv = tid >> 6;
    float aw = atts[lane], dw = attd[lane];  // att flat [4*16] == [64]
    __syncthreads();
    for (int base = blockIdx.x * 4; base < NN; base += gridDim.x * 4) {
        int row = base + wv;
        bool ok = row < NN;
        xs[wv][lane] = ok ? x[row * 64 + lane] : 0.0f;  // same-wave LDS: no barrier
        double acc = 0.0;
        #pragma unroll
        for (int k = 0; k < 64; ++k)
            acc += (double)xs[wv][k] * (double)w[lane][k];
        double s = acc * (double)aw, d = acc * (double)dw;
        #pragma unroll
        for (int off = 8; off; off >>= 1) {  // reduce within 16-lane head group
            s += __shfl_xor(s, off);
            d += __shfl_xor(d, off);
        }
        if (ok) {
            h[row * 64 + lane] = (float)acc;
            if ((lane & 15) == 0) {
                asrc[row * 4 + (lane >> 4)] = (float)s;
                adst[row * 4 + (lane >> 4)] = (float)d;
            }
        }
    }
}

// pass 1 over edges: segment max of leaky logits + in-degree count
__global__ __launch_bounds__(256) void k_edge_max(
    const int* __restrict__ ei, const float* __restrict__ asrc,
    const float* __restrict__ adst, float* __restrict__ m, int* __restrict__ cnt) {
    int e = blockIdx.x * blockDim.x + threadIdx.x;
    int stride = gridDim.x * blockDim.x;
    for (; e < NE; e += stride) {
        int s = ei[e];
        int d = ei[NE + e];
        float4 av = *(const float4*)(asrc + (size_t)s * 4);
        float4 bv = *(const float4*)(adst + (size_t)d * 4);
        atomicMaxF(&m[d * 4 + 0], lrelu(av.x + bv.x));
        atomicMaxF(&m[d * 4 + 1], lrelu(av.y + bv.y));
        atomicMaxF(&m[d * 4 + 2], lrelu(av.z + bv.z));
        atomicMaxF(&m[d * 4 + 3], lrelu(av.w + bv.w));
        atomicAdd(&cnt[d], 1);
    }
}

// pass 2: denom[dst] += exp(e - m[dst])  (fp64 accumulation)
__global__ __launch_bounds__(256) void k_edge_sum(
    const int* __restrict__ ei, const float* __restrict__ asrc,
    const float* __restrict__ adst, const float* __restrict__ m,
    double* __restrict__ denom) {
    int e = blockIdx.x * blockDim.x + threadIdx.x;
    int stride = gridDim.x * blockDim.x;
    for (; e < NE; e += stride) {
        int s = ei[e];
        int d = ei[NE + e];
        float4 av = *(const float4*)(asrc + (size_t)s * 4);
        float4 bv = *(const float4*)(adst + (size_t)d * 4);
        float4 mv = *(const float4*)(m + (size_t)d * 4);
        __hip_atomic_fetch_add(&denom[d * 4 + 0], (double)expf(lrelu(av.x + bv.x) - mv.x), __ATOMIC_RELAXED, __HIP_MEMORY_SCOPE_AGENT);
        __hip_atomic_fetch_add(&denom[d * 4 + 1], (double)expf(lrelu(av.y + bv.y) - mv.y), __ATOMIC_RELAXED, __HIP_MEMORY_SCOPE_AGENT);
        __hip_atomic_fetch_add(&denom[d * 4 + 2], (double)expf(lrelu(av.z + bv.z) - mv.z), __ATOMIC_RELAXED, __HIP_MEMORY_SCOPE_AGENT);
        __hip_atomic_fetch_add(&denom[d * 4 + 3], (double)expf(lrelu(av.w + bv.w) - mv.w), __ATOMIC_RELAXED, __HIP_MEMORY_SCOPE_AGENT);
    }
}

// pass 3: one wave per edge; lane = channel. agg[dst] += alpha * h[src]
template <typename T>
__global__ __launch_bounds__(256) void k_edge_agg(
    const int* __restrict__ ei, const float* __restrict__ asrc,
    const float* __restrict__ adst, const float* __restrict__ m,
    const double* __restrict__ denom, const float* __restrict__ h,
    T* __restrict__ agg) {
    int gt = blockIdx.x * 256 + threadIdx.x;
    int wave = gt >> 6, lane = gt & 63;
    int nw = (gridDim.x * 256) >> 6;
    int hh = lane >> 4;
    for (int e = wave; e < NE; e += nw) {
        int s = ei[e];
        int d = ei[NE + e];
        float ev = lrelu(asrc[s * 4 + hh] + adst[d * 4 + hh]);
        float ex = expf(ev - m[d * 4 + hh]);       // identical bits to k_edge_sum's exp
        double alpha = (double)ex / (denom[d * 4 + hh] + 1e-16);
        double msg = alpha * (double)h[(size_t)s * 64 + lane];
        __hip_atomic_fetch_add(&agg[(size_t)d * 64 + lane], (T)msg, __ATOMIC_RELAXED, __HIP_MEMORY_SCOPE_AGENT);
    }
}

// final: mean-div, out2 = aggm @ po^T, per-node norm over 64ch, threshold z>=2
template <typename T>
__global__ __launch_bounds__(256) void k_final(
    const T* __restrict__ agg, const int* __restrict__ cnt,
    const float* __restrict__ po, const float* __restrict__ gamma,
    const float* __restrict__ beta, float* __restrict__ out) {
    __shared__ float w[64][65];
    __shared__ double am[4][64];
    int tid = threadIdx.x;
    for (int i = tid; i < 4096; i += 256) w[i >> 6][i & 63] = po[i];
    int lane = tid & 63, wv = tid >> 6;
    float g = gamma[lane], b = beta[lane];
    __syncthreads();
    for (int base = blockIdx.x * 4; base < NN; base += gridDim.x * 4) {
        int n = base + wv;
        if (n >= NN) continue;
        int c = cnt[n];
        double inv_cnt = 1.0 / (double)(c > 0 ? c : 1);
        am[wv][lane] = (double)agg[(size_t)n * 64 + lane] * inv_cnt;  // same-wave LDS
        double acc = 0.0;
        #pragma unroll
        for (int k = 0; k < 64; ++k)
            acc += (double)w[lane][k] * am[wv][k];
        // mean/var across the 64 lanes (channels)
        double sum = acc;
        #pragma unroll
        for (int off = 32; off; off >>= 1) sum += __shfl_xor(sum, off);
        double mean = sum * (1.0 / 64.0);
        double dv = acc - mean;
        double sq = dv * dv;
        #pragma unroll
        for (int off = 32; off; off >>= 1) sq += __shfl_xor(sq, off);
        double var = sq * (1.0 / 64.0);
        double z = dv / sqrt(var + 1e-5);
        float zf = (float)(z * (double)g + (double)b);
        // LIF forward value == hard threshold: v = z/2 >= 1  <=>  z >= 2
        out[(size_t)n * 64 + lane] = (zf >= 2.0f) ? 1.0f : 0.0f;
    }
}

extern "C" void kernel_launch(void* const* d_in, const int* in_sizes, int n_in,
                              void* d_out, int out_size, void* d_ws, size_t ws_size,
                              hipStream_t stream) {
    const float* x     = (const float*)d_in[0];
    const int*   ei    = (const int*)d_in[1];   // harness pushes integers as int32
    const float* pw    = (const float*)d_in[2];
    const float* po    = (const float*)d_in[3];
    const float* atts  = (const float*)d_in[4];
    const float* attd  = (const float*)d_in[5];
    const float* gamma = (const float*)d_in[6];
    const float* beta  = (const float*)d_in[7];
    float* out = (float*)d_out;

    char* base = (char*)d_ws;
    size_t off = 0;
    auto alloc = [&](size_t b) { void* p = base + off; off += (b + 255) & ~(size_t)255; return p; };
    float* h      = (float*)alloc((size_t)NN * 64 * 4);
    float* asrc   = (float*)alloc((size_t)NN * 16);
    float* adst   = (float*)alloc((size_t)NN * 16);
    float* m      = (float*)alloc((size_t)NN * 16);
    int*   cnt    = (int*)alloc((size_t)NN * 4);
    double* denom = (double*)alloc((size_t)NN * 32);
    bool f64 = (ws_size >= off + (size_t)NN * 64 * 8 + 256);
    double* agg64 = nullptr;
    float*  agg32 = nullptr;
    if (f64) agg64 = (double*)alloc((size_t)NN * 64 * 8);
    else     agg32 = out;  // fallback: fp32 agg aliased into d_out (in-place-safe in k_final)

    hipMemsetAsync(cnt,   0, (size_t)NN * 4, stream);
    hipMemsetAsync(denom, 0, (size_t)NN * 32, stream);
    if (f64) hipMemsetAsync(agg64, 0, (size_t)NN * 64 * 8, stream);
    else     hipMemsetAsync(agg32, 0, (size_t)NN * 64 * 4, stream);
    k_init_m<<<(NN * 4 + 255) / 256, 256, 0, stream>>>(m);

    k_proj<<<1024, 256, 0, stream>>>(x, pw, atts, attd, h, asrc, adst);
    k_edge_max<<<4096, 256, 0, stream>>>(ei, asrc, adst, m, cnt);
    k_edge_sum<<<4096, 256, 0, stream>>>(ei, asrc, adst, m, denom);
    if (f64) {
        k_edge_agg<double><<<16384, 256, 0, stream>>>(ei, asrc, adst, m, denom, h, agg64);
        k_final<double><<<2048, 256, 0, stream>>>(agg64, cnt, po, gamma, beta, out);
    } else {
        k_edge_agg<float><<<16384, 256, 0, stream>>>(ei, asrc, adst, m, denom, h, agg32);
        k_final<float><<<2048, 256, 0, stream>>>(agg32, cnt, po, gamma, beta, out);
    }
}

// Round 3
// 546.293 us; speedup vs baseline: 2.4669x; 2.4669x over previous
//
#include <hip/hip_runtime.h>
#include <math.h>

#define NN 100000
#define NE 1600000
#define NCH 98   // ceil(NN/1024)

__device__ __forceinline__ float lrelu(float t) { return t >= 0.0f ? t : 0.2f * t; }

// h = x @ W^T (fp64 acc), att logits a_src/a_dst via per-head shuffle reduce.
__global__ __launch_bounds__(256) void k_proj(
    const float* __restrict__ x, const float* __restrict__ pw,
    const float* __restrict__ atts, const float* __restrict__ attd,
    float* __restrict__ h, float* __restrict__ asrc, float* __restrict__ adst) {
    __shared__ float w[64][65];
    __shared__ float xs[4][64];
    int tid = threadIdx.x;
    for (int i = tid; i < 4096; i += 256) w[i >> 6][i & 63] = pw[i];
    int lane = tid & 63, wv = tid >> 6;
    float aw = atts[lane], dw = attd[lane];
    __syncthreads();
    for (int base = blockIdx.x * 4; base < NN; base += gridDim.x * 4) {
        int row = base + wv;
        bool ok = row < NN;
        xs[wv][lane] = ok ? x[row * 64 + lane] : 0.0f;  // same-wave LDS: no barrier
        double acc = 0.0;
        #pragma unroll
        for (int k = 0; k < 64; ++k)
            acc += (double)xs[wv][k] * (double)w[lane][k];
        double s = acc * (double)aw, d = acc * (double)dw;
        #pragma unroll
        for (int off = 8; off; off >>= 1) {
            s += __shfl_xor(s, off);
            d += __shfl_xor(d, off);
        }
        if (ok) {
            h[row * 64 + lane] = (float)acc;
            if ((lane & 15) == 0) {
                asrc[row * 4 + (lane >> 4)] = (float)s;
                adst[row * 4 + (lane >> 4)] = (float)d;
            }
        }
    }
}

__global__ __launch_bounds__(256) void k_count(const int* __restrict__ ei, int* __restrict__ cnt) {
    int e = blockIdx.x * 256 + threadIdx.x;
    if (e < NE) atomicAdd(&cnt[ei[NE + e]], 1);
}

// in-place exclusive scan of cnt per 1024-chunk; chunk totals to part[]
__global__ __launch_bounds__(1024) void k_scan1(int* __restrict__ cnt, int* __restrict__ part) {
    __shared__ int s[1024];
    int tid = threadIdx.x, i = blockIdx.x * 1024 + tid;
    int v = (i < NN) ? cnt[i] : 0;
    s[tid] = v; __syncthreads();
    for (int off = 1; off < 1024; off <<= 1) {
        int t = (tid >= off) ? s[tid - off] : 0; __syncthreads();
        s[tid] += t; __syncthreads();
    }
    if (i < NN) cnt[i] = s[tid] - v;                 // exclusive within chunk
    if (tid == 1023) part[blockIdx.x] = s[1023];     // chunk total
}

__global__ void k_scan2(int* __restrict__ part) {
    if (threadIdx.x == 0) {
        int run = 0;
        for (int j = 0; j < NCH; ++j) { int t = part[j]; part[j] = run; run += t; }
    }
}

__global__ __launch_bounds__(1024) void k_scan3(
    const int* __restrict__ cnt, const int* __restrict__ part,
    int* __restrict__ rowptr, int* __restrict__ fill) {
    int i = blockIdx.x * 1024 + threadIdx.x;
    if (i < NN) { int rp = cnt[i] + part[i >> 10]; rowptr[i] = rp; fill[i] = rp; }
    if (i == 0) rowptr[NN] = NE;
}

__global__ __launch_bounds__(256) void k_scatter(
    const int* __restrict__ ei, int* __restrict__ fill, int* __restrict__ csr) {
    int e = blockIdx.x * 256 + threadIdx.x;
    if (e < NE) {
        int s = ei[e], d = ei[NE + e];
        int pos = atomicAdd(&fill[d], 1);
        csr[pos] = s;
    }
}

// fused per-node: softmax over incident edges + gather-agg + mean + GEMM + norm + threshold
__global__ __launch_bounds__(256) void k_node(
    const int* __restrict__ rowptr, const int* __restrict__ csr,
    const float* __restrict__ asrc, const float* __restrict__ adst,
    const float* __restrict__ h, const float* __restrict__ po,
    const float* __restrict__ gamma, const float* __restrict__ beta,
    float* __restrict__ out) {
    __shared__ float w[64][65];
    __shared__ double am[4][64];
    __shared__ __align__(16) float exl[4][64][4];
    __shared__ int sl[4][64];
    int tid = threadIdx.x;
    for (int i = tid; i < 4096; i += 256) w[i >> 6][i & 63] = po[i];
    int lane = tid & 63, wv = tid >> 6, hh = lane >> 4;
    float g = gamma[lane], b = beta[lane];
    __syncthreads();
    const float NINF = __int_as_float(0xff800000);
    for (int n = blockIdx.x * 4 + wv; n < NN; n += gridDim.x * 4) {
        int r0 = rowptr[n], deg = rowptr[n + 1] - r0;
        float4 bd = *(const float4*)(adst + (size_t)n * 4);
        double acc = 0.0;
        if (deg <= 64) {
            int s_e = 0;
            float4 lg = make_float4(NINF, NINF, NINF, NINF);
            if (lane < deg) {
                s_e = csr[r0 + lane];
                float4 av = *(const float4*)(asrc + (size_t)s_e * 4);
                lg.x = lrelu(av.x + bd.x); lg.y = lrelu(av.y + bd.y);
                lg.z = lrelu(av.z + bd.z); lg.w = lrelu(av.w + bd.w);
            }
            float4 mx = lg;
            #pragma unroll
            for (int off = 32; off; off >>= 1) {
                mx.x = fmaxf(mx.x, __shfl_xor(mx.x, off));
                mx.y = fmaxf(mx.y, __shfl_xor(mx.y, off));
                mx.z = fmaxf(mx.z, __shfl_xor(mx.z, off));
                mx.w = fmaxf(mx.w, __shfl_xor(mx.w, off));
            }
            float4 ex = make_float4(0.f, 0.f, 0.f, 0.f);
            if (lane < deg) {
                ex.x = expf(lg.x - mx.x); ex.y = expf(lg.y - mx.y);
                ex.z = expf(lg.z - mx.z); ex.w = expf(lg.w - mx.w);
            }
            double s0 = ex.x, s1 = ex.y, s2 = ex.z, s3 = ex.w;
            #pragma unroll
            for (int off = 32; off; off >>= 1) {
                s0 += __shfl_xor(s0, off); s1 += __shfl_xor(s1, off);
                s2 += __shfl_xor(s2, off); s3 += __shfl_xor(s3, off);
            }
            sl[wv][lane] = s_e;                       // same-wave LDS, no barrier
            *(float4*)&exl[wv][lane][0] = ex;
            double den = hh == 0 ? s0 : hh == 1 ? s1 : hh == 2 ? s2 : s3;
            double inv = 1.0 / (den + 1e-16);
            for (int e = 0; e < deg; ++e) {
                int s = sl[wv][e];
                double alpha = (double)exl[wv][e][hh] * inv;
                acc += alpha * (double)h[(size_t)s * 64 + lane];
            }
        } else {  // deg > 64: lane-strided, recompute path
            float4 mx = make_float4(NINF, NINF, NINF, NINF);
            for (int e = lane; e < deg; e += 64) {
                int s = csr[r0 + e];
                float4 av = *(const float4*)(asrc + (size_t)s * 4);
                mx.x = fmaxf(mx.x, lrelu(av.x + bd.x)); mx.y = fmaxf(mx.y, lrelu(av.y + bd.y));
                mx.z = fmaxf(mx.z, lrelu(av.z + bd.z)); mx.w = fmaxf(mx.w, lrelu(av.w + bd.w));
            }
            #pragma unroll
            for (int off = 32; off; off >>= 1) {
                mx.x = fmaxf(mx.x, __shfl_xor(mx.x, off));
                mx.y = fmaxf(mx.y, __shfl_xor(mx.y, off));
                mx.z = fmaxf(mx.z, __shfl_xor(mx.z, off));
                mx.w = fmaxf(mx.w, __shfl_xor(mx.w, off));
            }
            double s0 = 0, s1 = 0, s2 = 0, s3 = 0;
            for (int e = lane; e < deg; e += 64) {
                int s = csr[r0 + e];
                float4 av = *(const float4*)(asrc + (size_t)s * 4);
                s0 += (double)expf(lrelu(av.x + bd.x) - mx.x);
                s1 += (double)expf(lrelu(av.y + bd.y) - mx.y);
                s2 += (double)expf(lrelu(av.z + bd.z) - mx.z);
                s3 += (double)expf(lrelu(av.w + bd.w) - mx.w);
            }
            #pragma unroll
            for (int off = 32; off; off >>= 1) {
                s0 += __shfl_xor(s0, off); s1 += __shfl_xor(s1, off);
                s2 += __shfl_xor(s2, off); s3 += __shfl_xor(s3, off);
            }
            double den = hh == 0 ? s0 : hh == 1 ? s1 : hh == 2 ? s2 : s3;
            double inv = 1.0 / (den + 1e-16);
            float mxh = hh == 0 ? mx.x : hh == 1 ? mx.y : hh == 2 ? mx.z : mx.w;
            float bdh = hh == 0 ? bd.x : hh == 1 ? bd.y : hh == 2 ? bd.z : bd.w;
            for (int e = 0; e < deg; ++e) {
                int s = csr[r0 + e];
                float ev = lrelu(asrc[(size_t)s * 4 + hh] + bdh);
                float exe = expf(ev - mxh);
                acc += (double)exe * inv * (double)h[(size_t)s * 64 + lane];
            }
        }
        double invc = 1.0 / (double)(deg > 0 ? deg : 1);
        am[wv][lane] = acc * invc;                    // same-wave LDS
        double a2 = 0.0;
        #pragma unroll
        for (int k = 0; k < 64; ++k) a2 += (double)w[lane][k] * am[wv][k];
        double sum = a2;
        #pragma unroll
        for (int off = 32; off; off >>= 1) sum += __shfl_xor(sum, off);
        double mean = sum * (1.0 / 64.0);
        double dv = a2 - mean, sq = dv * dv;
        #pragma unroll
        for (int off = 32; off; off >>= 1) sq += __shfl_xor(sq, off);
        double var = sq * (1.0 / 64.0);
        double z = dv / sqrt(var + 1e-5);
        float zf = (float)(z * (double)g + (double)b);
        out[(size_t)n * 64 + lane] = (zf >= 2.0f) ? 1.0f : 0.0f;  // LIF fwd == z >= 2
    }
}

extern "C" void kernel_launch(void* const* d_in, const int* in_sizes, int n_in,
                              void* d_out, int out_size, void* d_ws, size_t ws_size,
                              hipStream_t stream) {
    const float* x     = (const float*)d_in[0];
    const int*   ei    = (const int*)d_in[1];   // harness pushes integers as int32
    const float* pw    = (const float*)d_in[2];
    const float* po    = (const float*)d_in[3];
    const float* atts  = (const float*)d_in[4];
    const float* attd  = (const float*)d_in[5];
    const float* gamma = (const float*)d_in[6];
    const float* beta  = (const float*)d_in[7];
    float* out = (float*)d_out;

    char* base = (char*)d_ws;
    size_t off = 0;
    auto alloc = [&](size_t b) { void* p = base + off; off += (b + 255) & ~(size_t)255; return p; };
    float* h      = (float*)alloc((size_t)NN * 64 * 4);
    float* asrc   = (float*)alloc((size_t)NN * 16);
    float* adst   = (float*)alloc((size_t)NN * 16);
    int*   rowptr = (int*)alloc(((size_t)NN + 1) * 4);
    int*   csr    = (int*)alloc((size_t)NE * 4);
    int*   part   = (int*)alloc((size_t)NCH * 4);
    // cnt & fill alias d_out (only live before k_node, which overwrites all of out)
    int* fill = (int*)out;
    int* cnt  = (int*)out + NN;

    hipMemsetAsync(cnt, 0, (size_t)NN * 4, stream);
    k_count<<<NE / 256, 256, 0, stream>>>(ei, cnt);
    k_scan1<<<NCH, 1024, 0, stream>>>(cnt, part);
    k_scan2<<<1, 64, 0, stream>>>(part);
    k_scan3<<<NCH, 1024, 0, stream>>>(cnt, part, rowptr, fill);
    k_scatter<<<NE / 256, 256, 0, stream>>>(ei, fill, csr);
    k_proj<<<1024, 256, 0, stream>>>(x, pw, atts, attd, h, asrc, adst);
    k_node<<<6250, 256, 0, stream>>>(rowptr, csr, asrc, adst, h, po, gamma, beta, out);
}